// Round 1
// baseline (93.027 us; speedup 1.0000x reference)
//
#include <hip/hip_runtime.h>
#include <stdint.h>

// Problem constants (fixed by the reference).
#define BB 4
#define NN 4096
#define MM 4096
#define CC 16
#define KMAX 128

// Output layout (flat float32, reference return order).
static constexpr int LOCSR_OFF = 0;                        // B*N*3
static constexpr int DATAR_OFF = BB * NN * 3;              // 49152
static constexpr int IDXS_OFF  = DATAR_OFF + BB * NN * CC; // 311296
static constexpr int NB_OFF    = IDXS_OFF + BB * NN;       // 327680

// radius as f32 (jnp weak-scalar cast), R^2 as double product cast to f32
static constexpr float RAD_F = 0.14f;
static constexpr float R2F   = (float)(0.14 * 0.14);

// Hash-grid limits
static constexpr int MAXC    = 96 * 96 * 96;   // max cells per batch
static constexpr int CSTRIDE = MAXC + 8;       // cell_start stride per batch

// ---------------- K0: per-batch partial bbox (16 blocks/batch) ----------------
// pmm[blk*6 + {0..5}] = {min x,y,z, max x,y,z} over this block's 256 elements.
__global__ void __launch_bounds__(256) k_bbox(const float* __restrict__ locs,
                                              float* __restrict__ pmm) {
    int blk = blockIdx.x;
    int b = blk >> 4, s = blk & 15, t = threadIdx.x;
    int i = s * 256 + t;
    const float* p = locs + (b * NN + i) * 3;
    float x0 = p[0], x1 = p[1], x2 = p[2];
    __shared__ float sm[6][256];
    sm[0][t] = x0; sm[1][t] = x1; sm[2][t] = x2;
    sm[3][t] = x0; sm[4][t] = x1; sm[5][t] = x2;
    __syncthreads();
    for (int st = 128; st > 0; st >>= 1) {
        if (t < st) {
            sm[0][t] = fminf(sm[0][t], sm[0][t + st]);
            sm[1][t] = fminf(sm[1][t], sm[1][t + st]);
            sm[2][t] = fminf(sm[2][t], sm[2][t + st]);
            sm[3][t] = fmaxf(sm[3][t], sm[3][t + st]);
            sm[4][t] = fmaxf(sm[4][t], sm[4][t + st]);
            sm[5][t] = fmaxf(sm[5][t], sm[5][t + st]);
        }
        __syncthreads();
    }
    if (t == 0) {
        float* o = pmm + blk * 6;
        o[0] = sm[0][0]; o[1] = sm[1][0]; o[2] = sm[2][0];
        o[3] = sm[3][0]; o[4] = sm[4][0]; o[5] = sm[5][0];
    }
}

// ---------------- K1: params + keys + stable rank sort + scatter ----------------
// 256 blocks x 1024 threads. Each block: reduce 16 bbox partials (thread 0,
// deterministic -> identical params in every block; blk%64==0 also writes gp),
// compute all 4096 combined keys (cell*4096+i) into LDS, then rank via
// register-held chunks + v_readlane broadcast (1 ds_read_b128 per lane instead
// of 64 broadcast reads per wave). Epilogue unchanged from verified version.
__global__ void __launch_bounds__(1024) k_rank(const float* __restrict__ locs,
                                               const float* __restrict__ data,
                                               const float* __restrict__ pmm,
                                               float* __restrict__ out,
                                               float4* __restrict__ sp4,
                                               unsigned* __restrict__ cs_sorted,
                                               float* __restrict__ gp) {
    __shared__ uint4 keys4[NN / 4];  // 16 KB
    __shared__ int partial[16][64];  // 4 KB
    __shared__ int s_dst[64];
    __shared__ float sp_low[3], sp_gdf[3];
    __shared__ int sp_s0, sp_s1;
    int blk = blockIdx.x;
    int b = blk >> 6;
    int t = threadIdx.x;
    int wave = t >> 6, lane = t & 63;

    if (t == 0) {
        const float* pm = pmm + b * 96;
        float mn0 = 1e30f, mn1 = 1e30f, mn2 = 1e30f;
        float mx0 = -1e30f, mx1 = -1e30f, mx2 = -1e30f;
#pragma unroll
        for (int k = 0; k < 16; ++k) {
            mn0 = fminf(mn0, pm[k * 6 + 0]);
            mn1 = fminf(mn1, pm[k * 6 + 1]);
            mn2 = fminf(mn2, pm[k * 6 + 2]);
            mx0 = fmaxf(mx0, pm[k * 6 + 3]);
            mx1 = fmaxf(mx1, pm[k * 6 + 4]);
            mx2 = fmaxf(mx2, pm[k * 6 + 5]);
        }
        float lo[3] = {mn0, mn1, mn2}, up[3] = {mx0, mx1, mx2};
        float low2[3], gdf[3];
        int gdi[3];
#pragma unroll
        for (int d = 0; d < 3; ++d) {
            // EXACT op sequence from the verified kernel
            float u = __fdiv_rn(__fsub_rn(up[d], lo[d]), RAD_F);
            u = fminf(fmaxf(u, 0.0f), 96.0f);
            float g = ceilf(u);
            float center = __fmul_rn(__fadd_rn(lo[d], up[d]), 0.5f);
            low2[d] = __fsub_rn(center, __fmul_rn(__fmul_rn(g, RAD_F), 0.5f));
            gdf[d] = g;
            gdi[d] = max((int)g, 1);
        }
        sp_low[0] = low2[0]; sp_low[1] = low2[1]; sp_low[2] = low2[2];
        sp_gdf[0] = gdf[0];  sp_gdf[1] = gdf[1];  sp_gdf[2] = gdf[2];
        sp_s0 = gdi[1] * gdi[2];
        sp_s1 = gdi[2];
        if ((blk & 63) == 0) {
            float* o = gp + b * 12;
            o[0] = low2[0]; o[1] = low2[1]; o[2] = low2[2];
            o[3] = gdf[0];  o[4] = gdf[1];  o[5] = gdf[2];
            ((int*)o)[6]  = gdi[1] * gdi[2];
            ((int*)o)[7]  = gdi[2];
            ((int*)o)[8]  = gdi[0] * gdi[1] * gdi[2];
            ((int*)o)[9]  = gdi[0];
            ((int*)o)[10] = gdi[1];
            ((int*)o)[11] = gdi[2];
        }
    }
    __syncthreads();

    // Keys for elements 4t..4t+3 via three coalesced float4 loads.
    {
        float l0 = sp_low[0], l1 = sp_low[1], l2 = sp_low[2];
        float g0 = sp_gdf[0], g1 = sp_gdf[1], g2 = sp_gdf[2];
        int s0 = sp_s0, s1 = sp_s1;
        const float4* lp = (const float4*)(locs + b * NN * 3) + t * 3;
        float4 A = lp[0], Bv = lp[1], Cv = lp[2];
        float ex[4] = {A.x, A.w, Bv.z, Cv.y};
        float ey[4] = {A.y, Bv.x, Bv.w, Cv.z};
        float ez[4] = {A.z, Bv.y, Cv.x, Cv.w};
        unsigned kk[4];
#pragma unroll
        for (int j = 0; j < 4; ++j) {
            float c0 = fminf(fmaxf(floorf(__fdiv_rn(__fsub_rn(ex[j], l0), RAD_F)), 0.0f), __fsub_rn(g0, 1.0f));
            float c1 = fminf(fmaxf(floorf(__fdiv_rn(__fsub_rn(ey[j], l1), RAD_F)), 0.0f), __fsub_rn(g1, 1.0f));
            float c2 = fminf(fmaxf(floorf(__fdiv_rn(__fsub_rn(ez[j], l2), RAD_F)), 0.0f), __fsub_rn(g2, 1.0f));
            unsigned cell = (unsigned)((int)c0 * s0 + (int)c1 * s1 + (int)c2);
            kk[j] = cell * 4096u + (unsigned)(4 * t + j);
        }
        keys4[t] = make_uint4(kk[0], kk[1], kk[2], kk[3]);
    }
    __syncthreads();

    int i = (blk & 63) * 64 + lane;
    unsigned key = ((const unsigned*)keys4)[i];
    // Wave's 256-key chunk held in registers: one b128 per lane.
    uint4 mv = keys4[wave * 64 + lane];
    int rank = 0;
#pragma unroll
    for (int s = 0; s < 64; ++s) {
        unsigned a  = (unsigned)__builtin_amdgcn_readlane((int)mv.x, s);
        unsigned b2 = (unsigned)__builtin_amdgcn_readlane((int)mv.y, s);
        unsigned c2 = (unsigned)__builtin_amdgcn_readlane((int)mv.z, s);
        unsigned d2 = (unsigned)__builtin_amdgcn_readlane((int)mv.w, s);
        rank += (int)(a < key) + (int)(b2 < key) + (int)(c2 < key) + (int)(d2 < key);
    }
    partial[wave][lane] = rank;
    __syncthreads();
    if (wave == 0) {
        int r = 0;
#pragma unroll
        for (int w = 0; w < 16; ++w) r += partial[w][lane];
        s_dst[lane] = r;
    }
    __syncthreads();
    if (wave == 0) {
        int src = b * NN + i;
        int dst = b * NN + s_dst[lane];
        float x = locs[src * 3 + 0], y = locs[src * 3 + 1], z = locs[src * 3 + 2];
        out[IDXS_OFF + dst] = (float)i;        // idxs[new] = old (as f32)
        out[LOCSR_OFF + dst * 3 + 0] = x;
        out[LOCSR_OFF + dst * 3 + 1] = y;
        out[LOCSR_OFF + dst * 3 + 2] = z;
        cs_sorted[dst] = key;                  // combined key; cell = key>>12
        // pn = (x*x + y*y) + z*z, numpy pairwise-sum (forward) order
        float pn = __fadd_rn(__fadd_rn(__fmul_rn(x, x), __fmul_rn(y, y)), __fmul_rn(z, z));
        sp4[dst] = make_float4(x, y, z, pn);
    } else if (wave <= 4) {
        int p = lane;
        int ii = (blk & 63) * 64 + p;
        int dst = b * NN + s_dst[p];
        int c = wave - 1;
        const float4* dsrc = (const float4*)(data + (b * NN + ii) * 16);
        float4* ddst = (float4*)(out + DATAR_OFF + dst * 16);
        ddst[c] = dsrc[c];
    }
}

// ---------------- K2: cell_start via binary search over sorted combined keys ----------------
__global__ void __launch_bounds__(256) k_cellstart(const unsigned* __restrict__ cs_sorted,
                                                   const float* __restrict__ gp,
                                                   int* __restrict__ cell_start) {
    int b = blockIdx.y;
    int nc = ((const int*)(gp + b * 12))[8];
    const unsigned* cs = cs_sorted + b * NN;
    int* cst = cell_start + b * CSTRIDE;
    for (int c = blockIdx.x * 256 + threadIdx.x; c <= nc; c += gridDim.x * 256) {
        int lo = 0, hi = NN; // first index with cell(cs[idx]) >= c
        while (lo < hi) {
            int mid = (lo + hi) >> 1;
            if ((int)(cs[mid] >> 12) < c) lo = mid + 1; else hi = mid;
        }
        cst[c] = lo;
    }
}

// ---------------- K3: grid-pruned radius search, wave per query ----------------
// All 18 cst bounds prefetched up-front (predicated 3x3 unroll -> register
// arrays, loads issue in parallel); early-exit removed so column scans are not
// control-dependent on prior ballots. Hit order (ascending sorted index) and
// dist2 math identical to the verified version.
__device__ inline void axis_range(float qd, float lo, int gd, int* c0, int* c1) {
    const float DL = RAD_F + 1e-4f; // conservative margin >> all fp rounding
    float vlo = (qd - DL - lo) / RAD_F;
    float vhi = (qd + DL - lo) / RAD_F;
    int a = (int)floorf(vlo), b = (int)floorf(vhi);
    *c0 = min(max(a, 0), gd - 1);
    *c1 = min(max(b, 0), gd - 1);
}

__global__ void __launch_bounds__(256, 8) k_neighbors(const float* __restrict__ qlocs,
                                                      const float4* __restrict__ sp4,
                                                      const int* __restrict__ cell_start,
                                                      const float* __restrict__ gp,
                                                      float* __restrict__ out) {
    int blk = blockIdx.x;        // 4096 total: b = blk>>10, 4 queries/block
    int b = blk >> 10;
    int wave = threadIdx.x >> 6, lane = threadIdx.x & 63;
    int m = (blk & 1023) * 4 + wave;
    const float* o = gp + b * 12;
    const int* oi = (const int*)o;
    int s0 = oi[6], s1 = oi[7];
    int gd0 = oi[9], gd1 = oi[10], gd2 = oi[11];
    const float* q = qlocs + (b * MM + m) * 3;
    float q0 = q[0], q1 = q[1], q2 = q[2];
    float qn = __fadd_rn(__fadd_rn(__fmul_rn(q0, q0), __fmul_rn(q1, q1)), __fmul_rn(q2, q2));
    int cx0, cx1, cy0, cy1, cz0, cz1;
    axis_range(q0, o[0], gd0, &cx0, &cx1);
    axis_range(q1, o[1], gd1, &cy0, &cy1);
    axis_range(q2, o[2], gd2, &cz0, &cz1);
    const float4* sp = sp4 + b * NN;
    const int* cst = cell_start + b * CSTRIDE;
    float* nb = out + NB_OFF + (b * MM + m) * KMAX;

    // Prefetch all column bounds (<=9 columns, fixed 3x3, invalid -> empty).
    int psA[3][3], peA[3][3];
#pragma unroll
    for (int dx = 0; dx < 3; ++dx) {
#pragma unroll
        for (int dy = 0; dy < 3; ++dy) {
            int cx = cx0 + dx, cy = cy0 + dy;
            bool v = (cx <= cx1) && (cy <= cy1);
            int base = cx * s0 + cy * s1;
            int i0 = v ? base + cz0 : 0;       // in-bounds when v; 0 otherwise
            int i1 = v ? base + cz1 + 1 : 0;
            int ps = cst[i0];
            int pe = cst[i1];
            psA[dx][dy] = v ? ps : 0;
            peA[dx][dy] = v ? pe : 0;
        }
    }

    int count = 0;
#pragma unroll
    for (int dx = 0; dx < 3; ++dx) {
#pragma unroll
        for (int dy = 0; dy < 3; ++dy) {
            int ps = psA[dx][dy], pe = peA[dx][dy];
            for (int p0 = ps; p0 < pe; p0 += 64) {
                int p = p0 + lane;
                float4 P = sp[p]; // <=63 over-read stays inside ws, masked below
                float cross = fmaf(q2, P.z, fmaf(q1, P.y, __fmul_rn(q0, P.x)));
                float dist2 = __fsub_rn(__fadd_rn(qn, P.w), __fmul_rn(2.0f, cross));
                bool hit = (p < pe) && (dist2 <= R2F);
                unsigned long long bal = __ballot(hit);
                if (hit) {
                    int pos = count + __popcll(bal & ((1ull << lane) - 1ull));
                    if (pos < KMAX) nb[pos] = (float)p;
                }
                count += __popcll(bal);
            }
        }
    }
    for (int j = count + lane; j < KMAX; j += 64) nb[j] = -1.0f;
}

extern "C" void kernel_launch(void* const* d_in, const int* in_sizes, int n_in,
                              void* d_out, int out_size, void* d_ws, size_t ws_size,
                              hipStream_t stream) {
    const float* locs  = (const float*)d_in[0];
    const float* data  = (const float*)d_in[1];
    const float* qlocs = (const float*)d_in[2];
    float* out = (float*)d_out;
    char* ws = (char*)d_ws;
    // ws layout
    float*    gp        = (float*)ws;                          // 4*12 floats (512 B reserved)
    float*    pmm       = (float*)(ws + 512);                  // 64*6 floats (4 KB reserved)
    unsigned* cs_sorted = (unsigned*)(ws + 4608);              // 64 KB
    float4*   sp4       = (float4*)(ws + 4608 + 65536);        // 256 KB (16B aligned)
    int* cell_start = (int*)(ws + 4608 + 65536 + BB * NN * sizeof(float4)); // ~14 MB

    k_bbox<<<BB * 16, 256, 0, stream>>>(locs, pmm);
    k_rank<<<BB * 64, 1024, 0, stream>>>(locs, data, pmm, out, sp4, cs_sorted, gp);
    k_cellstart<<<dim3(32, BB), 256, 0, stream>>>(cs_sorted, gp, cell_start);
    k_neighbors<<<BB * 1024, 256, 0, stream>>>(qlocs, sp4, cell_start, gp, out);
}